// Round 1
// baseline (948.765 us; speedup 1.0000x reference)
//
#include <hip/hip_runtime.h>
#include <hip/hip_bf16.h>

#define NN    50000
#define NE    800000
#define ETOT  (NE + NN)
#define D     128
#define NB    ((NN + 255) / 256)   // 196 scan blocks

__device__ __forceinline__ float gelu_tanh(float x) {
    // JAX default: approximate=True (tanh form)
    float x3 = x * x * x;
    float t  = tanhf(0.7978845608028654f * (x + 0.044715f * x3));
    return 0.5f * x * (1.0f + t);
}

// ---------------- CSR build ----------------

__global__ void count_k(const int* __restrict__ dstarr, int* __restrict__ counts) {
    int e = blockIdx.x * blockDim.x + threadIdx.x;
    if (e >= ETOT) return;
    int d = (e < NE) ? dstarr[e] : (e - NE);
    atomicAdd(&counts[d], 1);
}

__global__ void scan1_k(const int* __restrict__ counts, int* __restrict__ blk_sums) {
    __shared__ int sm[4];
    int i = blockIdx.x * 256 + threadIdx.x;
    int v = (i < NN) ? counts[i] : 0;
    #pragma unroll
    for (int o = 32; o; o >>= 1) v += __shfl_xor(v, o);
    int wv = threadIdx.x >> 6;
    if ((threadIdx.x & 63) == 0) sm[wv] = v;
    __syncthreads();
    if (threadIdx.x == 0) blk_sums[blockIdx.x] = sm[0] + sm[1] + sm[2] + sm[3];
}

__global__ void scan2_k(const int* __restrict__ blk_sums, int* __restrict__ blk_offs,
                        int* __restrict__ row_ptr) {
    if (threadIdx.x == 0 && blockIdx.x == 0) {
        int acc = 0;
        for (int b = 0; b < NB; ++b) { blk_offs[b] = acc; acc += blk_sums[b]; }
        row_ptr[NN] = acc;   // == ETOT
    }
}

__global__ void scan3_k(const int* __restrict__ counts, const int* __restrict__ blk_offs,
                        int* __restrict__ row_ptr, int* __restrict__ write_ptr) {
    __shared__ int s[256];
    int t = threadIdx.x;
    int i = blockIdx.x * 256 + t;
    int v = (i < NN) ? counts[i] : 0;
    s[t] = v;
    __syncthreads();
    for (int off = 1; off < 256; off <<= 1) {
        int x = (t >= off) ? s[t - off] : 0;
        __syncthreads();
        s[t] += x;
        __syncthreads();
    }
    int excl = s[t] - v + blk_offs[blockIdx.x];
    if (i < NN) { row_ptr[i] = excl; write_ptr[i] = excl; }
}

__global__ void scatter_k(const int* __restrict__ srcarr, const int* __restrict__ dstarr,
                          int* __restrict__ write_ptr, int* __restrict__ srcs) {
    int e = blockIdx.x * blockDim.x + threadIdx.x;
    if (e >= ETOT) return;
    int d, s;
    if (e < NE) { d = dstarr[e]; s = srcarr[e]; }
    else        { d = e - NE;    s = e - NE; }
    int pos = atomicAdd(&write_ptr[d], 1);
    srcs[pos] = s;
}

// ---------------- per-layer GEMM (wave per row) + alpha dots ----------------

__global__ __launch_bounds__(256) void gemm_k(
        const float* __restrict__ A, const float* __restrict__ W,
        const float* __restrict__ asv, const float* __restrict__ adv,
        float* __restrict__ XP, float* __restrict__ alpha_s, float* __restrict__ alpha_d) {
    int wid = (blockIdx.x * blockDim.x + threadIdx.x) >> 6;
    if (wid >= NN) return;
    int lane = threadIdx.x & 63;

    const float2* Ar = (const float2*)(A + (size_t)wid * D);
    float2 a = Ar[lane];                       // features 2*lane, 2*lane+1
    const float2* Wl = (const float2*)W;       // W[k][c], row k at k*64 float2

    float2 acc0 = {0.f, 0.f}, acc1 = {0.f, 0.f}, acc2 = {0.f, 0.f}, acc3 = {0.f, 0.f};
    #pragma unroll 4
    for (int k = 0; k < D; k += 4) {
        int q = k >> 1;
        float ak0 = __shfl(a.x, q);
        float ak1 = __shfl(a.y, q);
        float ak2 = __shfl(a.x, q + 1);
        float ak3 = __shfl(a.y, q + 1);
        float2 w0 = Wl[(k + 0) * 64 + lane];
        float2 w1 = Wl[(k + 1) * 64 + lane];
        float2 w2 = Wl[(k + 2) * 64 + lane];
        float2 w3 = Wl[(k + 3) * 64 + lane];
        acc0.x += ak0 * w0.x; acc0.y += ak0 * w0.y;
        acc1.x += ak1 * w1.x; acc1.y += ak1 * w1.y;
        acc2.x += ak2 * w2.x; acc2.y += ak2 * w2.y;
        acc3.x += ak3 * w3.x; acc3.y += ak3 * w3.y;
    }
    float2 o;
    o.x = (acc0.x + acc1.x) + (acc2.x + acc3.x);
    o.y = (acc0.y + acc1.y) + (acc2.y + acc3.y);
    ((float2*)(XP + (size_t)wid * D))[lane] = o;

    float2 as2 = ((const float2*)asv)[lane];
    float2 ad2 = ((const float2*)adv)[lane];
    float vs = o.x * as2.x + o.y * as2.y;
    float vd = o.x * ad2.x + o.y * ad2.y;
    #pragma unroll
    for (int off = 32; off; off >>= 1) {
        vs += __shfl_xor(vs, off);
        vd += __shfl_xor(vd, off);
    }
    if (lane == 0) { alpha_s[wid] = vs; alpha_d[wid] = vd; }
}

// ---------------- per-layer aggregation (wave per dst node) ----------------

__global__ __launch_bounds__(256) void agg_k(
        const int* __restrict__ row_ptr, const int* __restrict__ srcs,
        const float* __restrict__ alpha_s, const float* __restrict__ alpha_d,
        const float* __restrict__ XP, const float* __restrict__ bias,
        float* __restrict__ OUT, int apply_gelu) {
    int n = (blockIdx.x * blockDim.x + threadIdx.x) >> 6;
    if (n >= NN) return;
    int lane = threadIdx.x & 63;
    int beg = row_ptr[n], end = row_ptr[n + 1];
    float ad = alpha_d[n];

    float m = -3.4e38f;
    for (int i = beg + lane; i < end; i += 64) {
        int s = srcs[i];
        float e = alpha_s[s] + ad;
        e = e > 0.f ? e : 0.2f * e;
        m = fmaxf(m, e);
    }
    #pragma unroll
    for (int o = 32; o; o >>= 1) m = fmaxf(m, __shfl_xor(m, o));

    float denom = 0.f;
    for (int i = beg + lane; i < end; i += 64) {
        int s = srcs[i];
        float e = alpha_s[s] + ad;
        e = e > 0.f ? e : 0.2f * e;
        denom += __expf(e - m);
    }
    #pragma unroll
    for (int o = 32; o; o >>= 1) denom += __shfl_xor(denom, o);

    float acc0 = 0.f, acc1 = 0.f;
    for (int i = beg; i < end; ++i) {
        int s = srcs[i];                       // wave-uniform broadcast load
        float e = alpha_s[s] + ad;
        e = e > 0.f ? e : 0.2f * e;
        float wgt = __expf(e - m);
        const float* xr = XP + (size_t)s * D;
        acc0 += wgt * xr[lane];
        acc1 += wgt * xr[64 + lane];
    }
    float inv = 1.f / (denom + 1e-16f);
    float r0 = acc0 * inv + bias[lane];
    float r1 = acc1 * inv + bias[64 + lane];
    if (apply_gelu) { r0 = gelu_tanh(r0); r1 = gelu_tanh(r1); }
    OUT[(size_t)n * D + lane]      = r0;
    OUT[(size_t)n * D + 64 + lane] = r1;
}

// ---------------- launch ----------------

extern "C" void kernel_launch(void* const* d_in, const int* in_sizes, int n_in,
                              void* d_out, int out_size, void* d_ws, size_t ws_size,
                              hipStream_t stream) {
    const float* x    = (const float*)d_in[0];
    const int*   ei   = (const int*)d_in[1];        // [2, NE] int32
    const float* W    = (const float*)d_in[2];      // [3,128,128]
    const float* asrc = (const float*)d_in[3];      // [3,128]
    const float* adst = (const float*)d_in[4];      // [3,128]
    const float* bias = (const float*)d_in[5];      // [3,128]
    float* out = (float*)d_out;

    const int* src_arr = ei;
    const int* dst_arr = ei + NE;

    // workspace layout (floats/ints, 256B-ish aligned by construction)
    char* ws = (char*)d_ws;
    size_t off = 0;
    auto alloc = [&](size_t bytes) { char* p = ws + off; off += (bytes + 255) & ~(size_t)255; return p; };
    float* xp      = (float*)alloc((size_t)NN * D * sizeof(float));
    float* hbuf    = (float*)alloc((size_t)NN * D * sizeof(float));
    float* alpha_s = (float*)alloc(NN * sizeof(float));
    float* alpha_d = (float*)alloc(NN * sizeof(float));
    int* counts    = (int*)alloc(NN * sizeof(int));
    int* row_ptr   = (int*)alloc((NN + 1) * sizeof(int));
    int* write_ptr = (int*)alloc(NN * sizeof(int));
    int* blk_sums  = (int*)alloc(NB * sizeof(int));
    int* blk_offs  = (int*)alloc(NB * sizeof(int));
    int* srcs      = (int*)alloc((size_t)ETOT * sizeof(int));
    (void)ws_size; (void)in_sizes; (void)n_in; (void)out_size;

    // ---- CSR build (by dst), includes self loops ----
    hipMemsetAsync(counts, 0, NN * sizeof(int), stream);
    int eb = (ETOT + 255) / 256;
    count_k<<<eb, 256, 0, stream>>>(dst_arr, counts);
    scan1_k<<<NB, 256, 0, stream>>>(counts, blk_sums);
    scan2_k<<<1, 64, 0, stream>>>(blk_sums, blk_offs, row_ptr);
    scan3_k<<<NB, 256, 0, stream>>>(counts, blk_offs, row_ptr, write_ptr);
    scatter_k<<<eb, 256, 0, stream>>>(src_arr, dst_arr, write_ptr, srcs);

    // ---- 3 GAT layers ----
    const float* h_in[3]  = { x, hbuf, out };
    float*       h_out[3] = { hbuf, out, out };
    const int    gelu_f[3] = { 1, 1, 0 };

    int nwb = (NN + 3) / 4;   // 4 waves (nodes/rows) per 256-thread block
    for (int l = 0; l < 3; ++l) {
        const float* Wl  = W    + (size_t)l * D * D;
        const float* asl = asrc + (size_t)l * D;
        const float* adl = adst + (size_t)l * D;
        const float* bl  = bias + (size_t)l * D;
        gemm_k<<<nwb, 256, 0, stream>>>(h_in[l], Wl, asl, adl, xp, alpha_s, alpha_d);
        agg_k<<<nwb, 256, 0, stream>>>(row_ptr, srcs, alpha_s, alpha_d, xp, bl,
                                       h_out[l], gelu_f[l]);
    }
}

// Round 2
// 394.519 us; speedup vs baseline: 2.4049x; 2.4049x over previous
//
#include <hip/hip_runtime.h>
#include <hip/hip_bf16.h>

#define NN    50000
#define NE    800000
#define ETOT  (NE + NN)
#define D     128
#define NB    ((NN + 255) / 256)   // scan blocks
#define TM    64                   // gemm row tile
#define BK    16                   // gemm k tile
#define CAP   192                  // cached edges per node (deg ~ Poisson(17), max ~50)

__device__ __forceinline__ float gelu_tanh(float x) {
    float x3 = x * x * x;
    float t  = tanhf(0.7978845608028654f * (x + 0.044715f * x3));
    return 0.5f * x * (1.0f + t);
}

// ---------------- CSR build ----------------

__global__ void count_k(const int* __restrict__ dstarr, int* __restrict__ counts) {
    int e = blockIdx.x * blockDim.x + threadIdx.x;
    if (e >= ETOT) return;
    int d = (e < NE) ? dstarr[e] : (e - NE);
    atomicAdd(&counts[d], 1);
}

__global__ void scan1_k(const int* __restrict__ counts, int* __restrict__ blk_sums) {
    __shared__ int sm[4];
    int i = blockIdx.x * 256 + threadIdx.x;
    int v = (i < NN) ? counts[i] : 0;
    #pragma unroll
    for (int o = 32; o; o >>= 1) v += __shfl_xor(v, o);
    if ((threadIdx.x & 63) == 0) sm[threadIdx.x >> 6] = v;
    __syncthreads();
    if (threadIdx.x == 0) blk_sums[blockIdx.x] = sm[0] + sm[1] + sm[2] + sm[3];
}

__global__ void scan2_k(const int* __restrict__ blk_sums, int* __restrict__ blk_offs,
                        int* __restrict__ row_ptr) {
    if (threadIdx.x == 0 && blockIdx.x == 0) {
        int acc = 0;
        for (int b = 0; b < NB; ++b) { blk_offs[b] = acc; acc += blk_sums[b]; }
        row_ptr[NN] = acc;   // == ETOT
    }
}

__global__ void scan3_k(const int* __restrict__ counts, const int* __restrict__ blk_offs,
                        int* __restrict__ row_ptr, int* __restrict__ write_ptr) {
    __shared__ int s[256];
    int t = threadIdx.x;
    int i = blockIdx.x * 256 + t;
    int v = (i < NN) ? counts[i] : 0;
    s[t] = v;
    __syncthreads();
    for (int off = 1; off < 256; off <<= 1) {
        int x = (t >= off) ? s[t - off] : 0;
        __syncthreads();
        s[t] += x;
        __syncthreads();
    }
    int excl = s[t] - v + blk_offs[blockIdx.x];
    if (i < NN) { row_ptr[i] = excl; write_ptr[i] = excl; }
}

__global__ void scatter_k(const int* __restrict__ srcarr, const int* __restrict__ dstarr,
                          int* __restrict__ write_ptr, int* __restrict__ srcs) {
    int e = blockIdx.x * blockDim.x + threadIdx.x;
    if (e >= ETOT) return;
    int d, s;
    if (e < NE) { d = dstarr[e]; s = srcarr[e]; }
    else        { d = e - NE;    s = e - NE; }
    int pos = atomicAdd(&write_ptr[d], 1);
    srcs[pos] = s;
}

// ------------- wasd: per layer, was[k]=sum_c W[k][c]*as[c], wad likewise -------------

__global__ void wasd_k(const float* __restrict__ W, const float* __restrict__ asrc,
                       const float* __restrict__ adst, float* __restrict__ wasd) {
    int l = blockIdx.x;          // layer
    int t = threadIdx.x;         // 0..255
    int k = t & 127, which = t >> 7;
    const float* wr = W + (size_t)l * D * D + (size_t)k * D;
    const float* av = (which ? adst : asrc) + (size_t)l * D;
    float s = 0.f;
    #pragma unroll 4
    for (int c = 0; c < D; ++c) s += wr[c] * av[c];
    wasd[l * 256 + which * 128 + k] = s;
}

// ------------- tiled fp32 GEMM: XP = A @ W, plus fused alphas = A @ wasd -------------
// block: 256 threads, tile TM=64 rows x 128 cols, per-thread 4 rows x 8 cols

__global__ __launch_bounds__(256) void gemm_k(
        const float* __restrict__ A, const float* __restrict__ W,
        const float* __restrict__ wasd,   // [256]: W@a_src | W@a_dst for this layer
        float* __restrict__ XP, float* __restrict__ alpha_s, float* __restrict__ alpha_d) {
    __shared__ float At[BK][TM];     // 4 KB, transposed A tile
    __shared__ float Ws[BK * 128];   // 8 KB
    __shared__ float redS[4][TM];    // 1 KB
    __shared__ float redD[4][TM];    // 1 KB

    int t = threadIdx.x;
    int r0 = blockIdx.x * TM;

    // staging assignment: row rloc, k-group kg (kg wave-uniform: t>>6)
    int rloc = t & 63;
    int kg   = t >> 6;               // 0..3
    int grow = r0 + rloc; if (grow >= NN) grow = NN - 1;   // clamp (stores guarded)
    const float* Arow = A + (size_t)grow * D + kg * 4;

    // compute assignment: cols {4tx..4tx+3} u {64+4tx..}, rows ty*4..ty*4+3
    int tx = t & 15, ty = t >> 4;

    float4 accL[4] = {{0,0,0,0},{0,0,0,0},{0,0,0,0},{0,0,0,0}};
    float4 accH[4] = {{0,0,0,0},{0,0,0,0},{0,0,0,0},{0,0,0,0}};
    float ps = 0.f, pd = 0.f;

    for (int k0 = 0; k0 < D; k0 += BK) {
        // stage W tile (rows k0..k0+15, contiguous 8 KB)
        const float4* Wt = (const float4*)(W + (size_t)k0 * D);
        ((float4*)Ws)[t]       = Wt[t];
        ((float4*)Ws)[t + 256] = Wt[t + 256];
        // stage A tile transposed; fuse alpha partials (wasd loads are wave-uniform -> scalar)
        float4 a = *(const float4*)(Arow + k0);
        int kb = kg * 4;
        At[kb + 0][rloc] = a.x; At[kb + 1][rloc] = a.y;
        At[kb + 2][rloc] = a.z; At[kb + 3][rloc] = a.w;
        ps += a.x * wasd[k0 + kb + 0] + a.y * wasd[k0 + kb + 1]
            + a.z * wasd[k0 + kb + 2] + a.w * wasd[k0 + kb + 3];
        pd += a.x * wasd[128 + k0 + kb + 0] + a.y * wasd[128 + k0 + kb + 1]
            + a.z * wasd[128 + k0 + kb + 2] + a.w * wasd[128 + k0 + kb + 3];
        __syncthreads();

        #pragma unroll
        for (int k = 0; k < BK; ++k) {
            const float4* WR = (const float4*)(Ws + k * 128);
            float4 wlo = WR[tx];
            float4 whi = WR[16 + tx];
            float4 ra  = ((const float4*)(&At[k][0]))[ty];
            float ar[4] = {ra.x, ra.y, ra.z, ra.w};
            #pragma unroll
            for (int i = 0; i < 4; ++i) {
                accL[i].x += ar[i] * wlo.x; accL[i].y += ar[i] * wlo.y;
                accL[i].z += ar[i] * wlo.z; accL[i].w += ar[i] * wlo.w;
                accH[i].x += ar[i] * whi.x; accH[i].y += ar[i] * whi.y;
                accH[i].z += ar[i] * whi.z; accH[i].w += ar[i] * whi.w;
            }
        }
        __syncthreads();
    }

    // write XP
    #pragma unroll
    for (int i = 0; i < 4; ++i) {
        int r = r0 + ty * 4 + i;
        if (r < NN) {
            float4* o = (float4*)(XP + (size_t)r * D);
            o[tx]      = accL[i];
            o[16 + tx] = accH[i];
        }
    }
    // reduce alpha partials (4 k-groups per row)
    redS[kg][rloc] = ps;
    redD[kg][rloc] = pd;
    __syncthreads();
    if (t < TM) {
        int r = r0 + t;
        if (r < NN) {
            alpha_s[r] = (redS[0][t] + redS[1][t]) + (redS[2][t] + redS[3][t]);
            alpha_d[r] = (redD[0][t] + redD[1][t]) + (redD[2][t] + redD[3][t]);
        }
    }
}

// ---------------- aggregation: wave per dst node, LDS-cached (src, weight) ----------------

__global__ __launch_bounds__(256) void agg_k(
        const int* __restrict__ row_ptr, const int* __restrict__ srcs,
        const float* __restrict__ alpha_s, const float* __restrict__ alpha_d,
        const float* __restrict__ XP, const float* __restrict__ bias,
        float* __restrict__ OUT, int apply_gelu) {
    __shared__ int   sl[4][CAP];
    __shared__ float wl[4][CAP];
    int wv = threadIdx.x >> 6;
    int n  = (blockIdx.x * blockDim.x + threadIdx.x) >> 6;
    int lane = threadIdx.x & 63;
    int beg = row_ptr[n], end = row_ptr[n + 1], deg = end - beg;
    float ad = alpha_d[n];

    // pass 1: cache (s, e) per edge, wave-reduce max
    float m = -3.4e38f;
    for (int i = beg + lane; i < end; i += 64) {
        int s = srcs[i];
        float e = alpha_s[s] + ad;
        e = e > 0.f ? e : 0.2f * e;
        int idx = i - beg;
        if (idx < CAP) { sl[wv][idx] = s; wl[wv][idx] = e; }
        m = fmaxf(m, e);
    }
    #pragma unroll
    for (int o = 32; o; o >>= 1) m = fmaxf(m, __shfl_xor(m, o));
    __syncthreads();

    // pass 2: exp, overwrite cached weight, wave-reduce denom
    float denom = 0.f;
    for (int i = beg + lane; i < end; i += 64) {
        int idx = i - beg;
        float e;
        if (idx < CAP) e = wl[wv][idx];
        else { int s = srcs[i]; e = alpha_s[s] + ad; e = e > 0.f ? e : 0.2f * e; }
        float ex = __expf(e - m);
        if (idx < CAP) wl[wv][idx] = ex;
        denom += ex;
    }
    #pragma unroll
    for (int o = 32; o; o >>= 1) denom += __shfl_xor(denom, o);
    __syncthreads();

    // pass 3: serial gather, one float2 per lane covers the 128-float row
    float2 acc = {0.f, 0.f};
    for (int j = 0; j < deg; ++j) {
        int s; float wgt;
        if (j < CAP) { s = sl[wv][j]; wgt = wl[wv][j]; }
        else {
            s = srcs[beg + j];
            float e = alpha_s[s] + ad;
            e = e > 0.f ? e : 0.2f * e;
            wgt = __expf(e - m);
        }
        float2 xv = ((const float2*)(XP + (size_t)s * D))[lane];
        acc.x += wgt * xv.x;
        acc.y += wgt * xv.y;
    }
    float inv = 1.f / (denom + 1e-16f);
    float2 b2 = ((const float2*)bias)[lane];
    float r0 = acc.x * inv + b2.x;
    float r1 = acc.y * inv + b2.y;
    if (apply_gelu) { r0 = gelu_tanh(r0); r1 = gelu_tanh(r1); }
    ((float2*)(OUT + (size_t)n * D))[lane] = make_float2(r0, r1);
}

// ---------------- launch ----------------

extern "C" void kernel_launch(void* const* d_in, const int* in_sizes, int n_in,
                              void* d_out, int out_size, void* d_ws, size_t ws_size,
                              hipStream_t stream) {
    const float* x    = (const float*)d_in[0];
    const int*   ei   = (const int*)d_in[1];        // [2, NE] int32
    const float* W    = (const float*)d_in[2];      // [3,128,128]
    const float* asrc = (const float*)d_in[3];      // [3,128]
    const float* adst = (const float*)d_in[4];      // [3,128]
    const float* bias = (const float*)d_in[5];      // [3,128]
    float* out = (float*)d_out;

    const int* src_arr = ei;
    const int* dst_arr = ei + NE;

    char* ws = (char*)d_ws;
    size_t off = 0;
    auto alloc = [&](size_t bytes) { char* p = ws + off; off += (bytes + 255) & ~(size_t)255; return p; };
    float* xp      = (float*)alloc((size_t)NN * D * sizeof(float));
    float* hbuf    = (float*)alloc((size_t)NN * D * sizeof(float));
    float* alpha_s = (float*)alloc(NN * sizeof(float));
    float* alpha_d = (float*)alloc(NN * sizeof(float));
    float* wasd    = (float*)alloc(3 * 256 * sizeof(float));
    int* counts    = (int*)alloc(NN * sizeof(int));
    int* row_ptr   = (int*)alloc((NN + 1) * sizeof(int));
    int* write_ptr = (int*)alloc(NN * sizeof(int));
    int* blk_sums  = (int*)alloc(NB * sizeof(int));
    int* blk_offs  = (int*)alloc(NB * sizeof(int));
    int* srcs      = (int*)alloc((size_t)ETOT * sizeof(int));
    (void)ws_size; (void)in_sizes; (void)n_in; (void)out_size;

    // CSR build (by dst), includes self loops
    hipMemsetAsync(counts, 0, NN * sizeof(int), stream);
    int eb = (ETOT + 255) / 256;
    count_k<<<eb, 256, 0, stream>>>(dst_arr, counts);
    scan1_k<<<NB, 256, 0, stream>>>(counts, blk_sums);
    scan2_k<<<1, 64, 0, stream>>>(blk_sums, blk_offs, row_ptr);
    scan3_k<<<NB, 256, 0, stream>>>(counts, blk_offs, row_ptr, write_ptr);
    scatter_k<<<eb, 256, 0, stream>>>(src_arr, dst_arr, write_ptr, srcs);

    // per-layer projected attention vectors
    wasd_k<<<3, 256, 0, stream>>>(W, asrc, adst, wasd);

    // 3 GAT layers
    const float* h_in[3]  = { x, hbuf, out };
    float*       h_out[3] = { hbuf, out, out };
    const int    gelu_f[3] = { 1, 1, 0 };

    int gemm_blocks = (NN + TM - 1) / TM;     // 782
    int agg_blocks  = NN / 4;                 // 12500 (NN % 4 == 0)
    for (int l = 0; l < 3; ++l) {
        const float* Wl = W    + (size_t)l * D * D;
        const float* bl = bias + (size_t)l * D;
        gemm_k<<<gemm_blocks, 256, 0, stream>>>(h_in[l], Wl, wasd + l * 256,
                                                xp, alpha_s, alpha_d);
        agg_k<<<agg_blocks, 256, 0, stream>>>(row_ptr, srcs, alpha_s, alpha_d, xp, bl,
                                              h_out[l], gelu_f[l]);
    }
}

// Round 3
// 382.685 us; speedup vs baseline: 2.4792x; 1.0309x over previous
//
#include <hip/hip_runtime.h>
#include <hip/hip_bf16.h>

#define NN    50000
#define NE    800000
#define ETOT  (NE + NN)
#define D     128
#define NB    ((NN + 255) / 256)   // scan blocks
#define TM    64                   // gemm row tile
#define BK    16                   // gemm k tile

__device__ __forceinline__ float gelu_tanh(float x) {
    float x3 = x * x * x;
    float t  = tanhf(0.7978845608028654f * (x + 0.044715f * x3));
    return 0.5f * x * (1.0f + t);
}

// ---------------- CSR build ----------------

__global__ void count_k(const int* __restrict__ dstarr, int* __restrict__ counts) {
    int e = blockIdx.x * blockDim.x + threadIdx.x;
    if (e >= ETOT) return;
    int d = (e < NE) ? dstarr[e] : (e - NE);
    atomicAdd(&counts[d], 1);
}

__global__ void scan1_k(const int* __restrict__ counts, int* __restrict__ blk_sums) {
    __shared__ int sm[4];
    int i = blockIdx.x * 256 + threadIdx.x;
    int v = (i < NN) ? counts[i] : 0;
    #pragma unroll
    for (int o = 32; o; o >>= 1) v += __shfl_xor(v, o);
    if ((threadIdx.x & 63) == 0) sm[threadIdx.x >> 6] = v;
    __syncthreads();
    if (threadIdx.x == 0) blk_sums[blockIdx.x] = sm[0] + sm[1] + sm[2] + sm[3];
}

__global__ void scan2_k(const int* __restrict__ blk_sums, int* __restrict__ blk_offs,
                        int* __restrict__ row_ptr) {
    if (threadIdx.x == 0 && blockIdx.x == 0) {
        int acc = 0;
        for (int b = 0; b < NB; ++b) { blk_offs[b] = acc; acc += blk_sums[b]; }
        row_ptr[NN] = acc;   // == ETOT
    }
}

__global__ void scan3_k(const int* __restrict__ counts, const int* __restrict__ blk_offs,
                        int* __restrict__ row_ptr, int* __restrict__ write_ptr) {
    __shared__ int s[256];
    int t = threadIdx.x;
    int i = blockIdx.x * 256 + t;
    int v = (i < NN) ? counts[i] : 0;
    s[t] = v;
    __syncthreads();
    for (int off = 1; off < 256; off <<= 1) {
        int x = (t >= off) ? s[t - off] : 0;
        __syncthreads();
        s[t] += x;
        __syncthreads();
    }
    int excl = s[t] - v + blk_offs[blockIdx.x];
    if (i < NN) { row_ptr[i] = excl; write_ptr[i] = excl; }
}

__global__ void scatter_k(const int* __restrict__ srcarr, const int* __restrict__ dstarr,
                          int* __restrict__ write_ptr, int* __restrict__ srcs) {
    int e = blockIdx.x * blockDim.x + threadIdx.x;
    if (e >= ETOT) return;
    int d, s;
    if (e < NE) { d = dstarr[e]; s = srcarr[e]; }
    else        { d = e - NE;    s = e - NE; }
    int pos = atomicAdd(&write_ptr[d], 1);
    srcs[pos] = s;
}

// ------------- wasd: per layer, was[k]=sum_c W[k][c]*as[c], wad likewise -------------

__global__ void wasd_k(const float* __restrict__ W, const float* __restrict__ asrc,
                       const float* __restrict__ adst, float* __restrict__ wasd) {
    int l = blockIdx.x;
    int t = threadIdx.x;
    int k = t & 127, which = t >> 7;
    const float* wr = W + (size_t)l * D * D + (size_t)k * D;
    const float* av = (which ? adst : asrc) + (size_t)l * D;
    float s = 0.f;
    #pragma unroll 4
    for (int c = 0; c < D; ++c) s += wr[c] * av[c];
    wasd[l * 256 + which * 128 + k] = s;
}

// ------------- tiled fp32 GEMM: XP = A @ W, plus fused alphas = A @ wasd -------------

__global__ __launch_bounds__(256) void gemm_k(
        const float* __restrict__ A, const float* __restrict__ W,
        const float* __restrict__ wasd,
        float* __restrict__ XP, float* __restrict__ alpha_s, float* __restrict__ alpha_d) {
    __shared__ float At[BK][TM];
    __shared__ float Ws[BK * 128];
    __shared__ float redS[4][TM];
    __shared__ float redD[4][TM];

    int t = threadIdx.x;
    int r0 = blockIdx.x * TM;

    int rloc = t & 63;
    int kg   = t >> 6;
    int grow = r0 + rloc; if (grow >= NN) grow = NN - 1;
    const float* Arow = A + (size_t)grow * D + kg * 4;

    int tx = t & 15, ty = t >> 4;

    float4 accL[4] = {{0,0,0,0},{0,0,0,0},{0,0,0,0},{0,0,0,0}};
    float4 accH[4] = {{0,0,0,0},{0,0,0,0},{0,0,0,0},{0,0,0,0}};
    float ps = 0.f, pd = 0.f;

    for (int k0 = 0; k0 < D; k0 += BK) {
        const float4* Wt = (const float4*)(W + (size_t)k0 * D);
        ((float4*)Ws)[t]       = Wt[t];
        ((float4*)Ws)[t + 256] = Wt[t + 256];
        float4 a = *(const float4*)(Arow + k0);
        int kb = kg * 4;
        At[kb + 0][rloc] = a.x; At[kb + 1][rloc] = a.y;
        At[kb + 2][rloc] = a.z; At[kb + 3][rloc] = a.w;
        ps += a.x * wasd[k0 + kb + 0] + a.y * wasd[k0 + kb + 1]
            + a.z * wasd[k0 + kb + 2] + a.w * wasd[k0 + kb + 3];
        pd += a.x * wasd[128 + k0 + kb + 0] + a.y * wasd[128 + k0 + kb + 1]
            + a.z * wasd[128 + k0 + kb + 2] + a.w * wasd[128 + k0 + kb + 3];
        __syncthreads();

        #pragma unroll
        for (int k = 0; k < BK; ++k) {
            const float4* WR = (const float4*)(Ws + k * 128);
            float4 wlo = WR[tx];
            float4 whi = WR[16 + tx];
            float4 ra  = ((const float4*)(&At[k][0]))[ty];
            float ar[4] = {ra.x, ra.y, ra.z, ra.w};
            #pragma unroll
            for (int i = 0; i < 4; ++i) {
                accL[i].x += ar[i] * wlo.x; accL[i].y += ar[i] * wlo.y;
                accL[i].z += ar[i] * wlo.z; accL[i].w += ar[i] * wlo.w;
                accH[i].x += ar[i] * whi.x; accH[i].y += ar[i] * whi.y;
                accH[i].z += ar[i] * whi.z; accH[i].w += ar[i] * whi.w;
            }
        }
        __syncthreads();
    }

    #pragma unroll
    for (int i = 0; i < 4; ++i) {
        int r = r0 + ty * 4 + i;
        if (r < NN) {
            float4* o = (float4*)(XP + (size_t)r * D);
            o[tx]      = accL[i];
            o[16 + tx] = accH[i];
        }
    }
    redS[kg][rloc] = ps;
    redD[kg][rloc] = pd;
    __syncthreads();
    if (t < TM) {
        int r = r0 + t;
        if (r < NN) {
            alpha_s[r] = (redS[0][t] + redS[1][t]) + (redS[2][t] + redS[3][t]);
            alpha_d[r] = (redD[0][t] + redD[1][t]) + (redD[2][t] + redD[3][t]);
        }
    }
}

// ---------------- aggregation: wave per dst node, register-resident edges ----------------

__global__ __launch_bounds__(256) void agg_k(
        const int* __restrict__ row_ptr, const int* __restrict__ srcs,
        const float* __restrict__ alpha_s, const float* __restrict__ alpha_d,
        const float* __restrict__ XP, const float* __restrict__ bias,
        float* __restrict__ OUT, int apply_gelu) {
    int n = (blockIdx.x * blockDim.x + threadIdx.x) >> 6;
    int lane = threadIdx.x & 63;
    int beg = row_ptr[n], end = row_ptr[n + 1], deg = end - beg;
    float ad = alpha_d[n];

    if (deg <= 64) {
        // ---- one edge per lane: compute e, wave-reduce max & denom ----
        int sreg = 0;
        float e = -3.4e38f;
        if (lane < deg) {
            sreg = srcs[beg + lane];
            float v = alpha_s[sreg] + ad;
            e = v > 0.f ? v : 0.2f * v;
        }
        float m = e;
        #pragma unroll
        for (int o = 32; o; o >>= 1) m = fmaxf(m, __shfl_xor(m, o));
        float w = (lane < deg) ? __expf(e - m) : 0.f;
        float denom = w;
        #pragma unroll
        for (int o = 32; o; o >>= 1) denom += __shfl_xor(denom, o);

        // ---- gather: half-wave (32 lanes x float4 = 512B) per row, 4 rows in flight ----
        int half = lane >> 5, q = lane & 31;
        float4 acc0 = {0,0,0,0}, acc1 = {0,0,0,0};
        int j = 0;
        for (; j + 4 <= deg; j += 4) {
            int   s0 = __shfl(sreg, j + half);
            float w0 = __shfl(w,    j + half);
            int   s1 = __shfl(sreg, j + 2 + half);
            float w1 = __shfl(w,    j + 2 + half);
            float4 x0 = ((const float4*)(XP + (size_t)s0 * D))[q];
            float4 x1 = ((const float4*)(XP + (size_t)s1 * D))[q];
            acc0.x += w0 * x0.x; acc0.y += w0 * x0.y;
            acc0.z += w0 * x0.z; acc0.w += w0 * x0.w;
            acc1.x += w1 * x1.x; acc1.y += w1 * x1.y;
            acc1.z += w1 * x1.z; acc1.w += w1 * x1.w;
        }
        for (; j < deg; j += 2) {
            int ej = j + half;
            int   s0 = __shfl(sreg, ej < 63 ? ej : 63);
            float w0 = __shfl(w,    ej < 63 ? ej : 63);
            if (ej < deg) {
                float4 x0 = ((const float4*)(XP + (size_t)s0 * D))[q];
                acc0.x += w0 * x0.x; acc0.y += w0 * x0.y;
                acc0.z += w0 * x0.z; acc0.w += w0 * x0.w;
            }
        }
        float4 tot;
        tot.x = acc0.x + acc1.x; tot.y = acc0.y + acc1.y;
        tot.z = acc0.z + acc1.z; tot.w = acc0.w + acc1.w;
        tot.x += __shfl_xor(tot.x, 32);
        tot.y += __shfl_xor(tot.y, 32);
        tot.z += __shfl_xor(tot.z, 32);
        tot.w += __shfl_xor(tot.w, 32);

        if (half == 0) {
            float inv = 1.f / (denom + 1e-16f);
            float4 b4 = ((const float4*)bias)[q];
            float r0 = tot.x * inv + b4.x;
            float r1 = tot.y * inv + b4.y;
            float r2 = tot.z * inv + b4.z;
            float r3 = tot.w * inv + b4.w;
            if (apply_gelu) {
                r0 = gelu_tanh(r0); r1 = gelu_tanh(r1);
                r2 = gelu_tanh(r2); r3 = gelu_tanh(r3);
            }
            ((float4*)(OUT + (size_t)n * D))[q] = make_float4(r0, r1, r2, r3);
        }
    } else {
        // ---- rare fallback: generic 3-pass (deg > 64) ----
        float m = -3.4e38f;
        for (int i = beg + lane; i < end; i += 64) {
            int s = srcs[i];
            float v = alpha_s[s] + ad;
            v = v > 0.f ? v : 0.2f * v;
            m = fmaxf(m, v);
        }
        #pragma unroll
        for (int o = 32; o; o >>= 1) m = fmaxf(m, __shfl_xor(m, o));
        float denom = 0.f;
        for (int i = beg + lane; i < end; i += 64) {
            int s = srcs[i];
            float v = alpha_s[s] + ad;
            v = v > 0.f ? v : 0.2f * v;
            denom += __expf(v - m);
        }
        #pragma unroll
        for (int o = 32; o; o >>= 1) denom += __shfl_xor(denom, o);
        float2 acc = {0.f, 0.f};
        for (int i = beg; i < end; ++i) {
            int s = srcs[i];
            float v = alpha_s[s] + ad;
            v = v > 0.f ? v : 0.2f * v;
            float wgt = __expf(v - m);
            float2 xv = ((const float2*)(XP + (size_t)s * D))[lane];
            acc.x += wgt * xv.x;
            acc.y += wgt * xv.y;
        }
        float inv = 1.f / (denom + 1e-16f);
        float2 b2 = ((const float2*)bias)[lane];
        float r0 = acc.x * inv + b2.x;
        float r1 = acc.y * inv + b2.y;
        if (apply_gelu) { r0 = gelu_tanh(r0); r1 = gelu_tanh(r1); }
        ((float2*)(OUT + (size_t)n * D))[lane] = make_float2(r0, r1);
    }
}

// ---------------- launch ----------------

extern "C" void kernel_launch(void* const* d_in, const int* in_sizes, int n_in,
                              void* d_out, int out_size, void* d_ws, size_t ws_size,
                              hipStream_t stream) {
    const float* x    = (const float*)d_in[0];
    const int*   ei   = (const int*)d_in[1];
    const float* W    = (const float*)d_in[2];
    const float* asrc = (const float*)d_in[3];
    const float* adst = (const float*)d_in[4];
    const float* bias = (const float*)d_in[5];
    float* out = (float*)d_out;

    const int* src_arr = ei;
    const int* dst_arr = ei + NE;

    char* ws = (char*)d_ws;
    size_t off = 0;
    auto alloc = [&](size_t bytes) { char* p = ws + off; off += (bytes + 255) & ~(size_t)255; return p; };
    float* xp      = (float*)alloc((size_t)NN * D * sizeof(float));
    float* hbuf    = (float*)alloc((size_t)NN * D * sizeof(float));
    float* alpha_s = (float*)alloc(NN * sizeof(float));
    float* alpha_d = (float*)alloc(NN * sizeof(float));
    float* wasd    = (float*)alloc(3 * 256 * sizeof(float));
    int* counts    = (int*)alloc(NN * sizeof(int));
    int* row_ptr   = (int*)alloc((NN + 1) * sizeof(int));
    int* write_ptr = (int*)alloc(NN * sizeof(int));
    int* blk_sums  = (int*)alloc(NB * sizeof(int));
    int* blk_offs  = (int*)alloc(NB * sizeof(int));
    int* srcs      = (int*)alloc((size_t)ETOT * sizeof(int));
    (void)ws_size; (void)in_sizes; (void)n_in; (void)out_size;

    hipMemsetAsync(counts, 0, NN * sizeof(int), stream);
    int eb = (ETOT + 255) / 256;
    count_k<<<eb, 256, 0, stream>>>(dst_arr, counts);
    scan1_k<<<NB, 256, 0, stream>>>(counts, blk_sums);
    scan2_k<<<1, 64, 0, stream>>>(blk_sums, blk_offs, row_ptr);
    scan3_k<<<NB, 256, 0, stream>>>(counts, blk_offs, row_ptr, write_ptr);
    scatter_k<<<eb, 256, 0, stream>>>(src_arr, dst_arr, write_ptr, srcs);

    wasd_k<<<3, 256, 0, stream>>>(W, asrc, adst, wasd);

    const float* h_in[3]  = { x, hbuf, out };
    float*       h_out[3] = { hbuf, out, out };
    const int    gelu_f[3] = { 1, 1, 0 };

    int gemm_blocks = (NN + TM - 1) / TM;
    int agg_blocks  = NN / 4;
    for (int l = 0; l < 3; ++l) {
        const float* Wl = W    + (size_t)l * D * D;
        const float* bl = bias + (size_t)l * D;
        gemm_k<<<gemm_blocks, 256, 0, stream>>>(h_in[l], Wl, wasd + l * 256,
                                                xp, alpha_s, alpha_d);
        agg_k<<<agg_blocks, 256, 0, stream>>>(row_ptr, srcs, alpha_s, alpha_d, xp, bl,
                                              h_out[l], gelu_f[l]);
    }
}

// Round 4
// 341.710 us; speedup vs baseline: 2.7765x; 1.1199x over previous
//
#include <hip/hip_runtime.h>
#include <hip/hip_bf16.h>
#include <hip/hip_fp16.h>

#define NN    50000
#define NE    800000
#define ETOT  (NE + NN)
#define D     128
#define NB    ((NN + 255) / 256)   // scan blocks

__device__ __forceinline__ float gelu_tanh(float x) {
    float x3 = x * x * x;
    float t  = tanhf(0.7978845608028654f * (x + 0.044715f * x3));
    return 0.5f * x * (1.0f + t);
}

// ---------------- CSR build ----------------

__global__ void count_k(const int* __restrict__ dstarr, int* __restrict__ counts) {
    int e = blockIdx.x * blockDim.x + threadIdx.x;
    if (e >= ETOT) return;
    int d = (e < NE) ? dstarr[e] : (e - NE);
    atomicAdd(&counts[d], 1);
}

__global__ void scan1_k(const int* __restrict__ counts, int* __restrict__ blk_sums) {
    __shared__ int sm[4];
    int i = blockIdx.x * 256 + threadIdx.x;
    int v = (i < NN) ? counts[i] : 0;
    #pragma unroll
    for (int o = 32; o; o >>= 1) v += __shfl_xor(v, o);
    if ((threadIdx.x & 63) == 0) sm[threadIdx.x >> 6] = v;
    __syncthreads();
    if (threadIdx.x == 0) blk_sums[blockIdx.x] = sm[0] + sm[1] + sm[2] + sm[3];
}

__global__ void scan2_k(const int* __restrict__ blk_sums, int* __restrict__ blk_offs,
                        int* __restrict__ row_ptr) {
    if (threadIdx.x == 0 && blockIdx.x == 0) {
        int acc = 0;
        for (int b = 0; b < NB; ++b) { blk_offs[b] = acc; acc += blk_sums[b]; }
        row_ptr[NN] = acc;
    }
}

__global__ void scan3_k(const int* __restrict__ counts, const int* __restrict__ blk_offs,
                        int* __restrict__ row_ptr, int* __restrict__ write_ptr) {
    __shared__ int s[256];
    int t = threadIdx.x;
    int i = blockIdx.x * 256 + t;
    int v = (i < NN) ? counts[i] : 0;
    s[t] = v;
    __syncthreads();
    for (int off = 1; off < 256; off <<= 1) {
        int x = (t >= off) ? s[t - off] : 0;
        __syncthreads();
        s[t] += x;
        __syncthreads();
    }
    int excl = s[t] - v + blk_offs[blockIdx.x];
    if (i < NN) { row_ptr[i] = excl; write_ptr[i] = excl; }
}

__global__ void scatter_k(const int* __restrict__ srcarr, const int* __restrict__ dstarr,
                          int* __restrict__ write_ptr, int* __restrict__ srcs) {
    int e = blockIdx.x * blockDim.x + threadIdx.x;
    if (e >= ETOT) return;
    int d, s;
    if (e < NE) { d = dstarr[e]; s = srcarr[e]; }
    else        { d = e - NE;    s = e - NE; }
    int pos = atomicAdd(&write_ptr[d], 1);
    srcs[pos] = s;
}

// ------------- wasd: per layer, was[k]=sum_c W[k][c]*as[c], wad likewise -------------

__global__ void wasd_k(const float* __restrict__ W, const float* __restrict__ asrc,
                       const float* __restrict__ adst, float* __restrict__ wasd) {
    int l = blockIdx.x;
    int t = threadIdx.x;
    int k = t & 127, which = t >> 7;
    const float* wr = W + (size_t)l * D * D + (size_t)k * D;
    const float* av = (which ? adst : asrc) + (size_t)l * D;
    float s = 0.f;
    #pragma unroll 4
    for (int c = 0; c < D; ++c) s += wr[c] * av[c];
    wasd[l * 256 + which * 128 + k] = s;
}

// ------------- tiled fp32 GEMM: XP = A @ W (+ fused fp32 alphas = A @ wasd) -------------
// 256 threads; tile 64 rows x 64 cols; BK=32; reg double-buffered staging.
// grid: blockIdx.x = 2*row_tile + col_half

template <typename OutT>
__global__ __launch_bounds__(256) void gemm_k(
        const float* __restrict__ A, const float* __restrict__ W,
        const float* __restrict__ wasd,
        OutT* __restrict__ XP, float* __restrict__ alpha_s, float* __restrict__ alpha_d) {
    __shared__ float At[32][64];     // [k][row] 8 KB
    __shared__ float Ws[32][64];     // [k][col] 8 KB
    __shared__ float redS[64][8];
    __shared__ float redD[64][8];

    int t  = threadIdx.x;
    int ct = blockIdx.x & 1;
    int rt = blockIdx.x >> 1;
    int r0 = rt * 64;
    int c0 = ct * 64;

    int tx = t & 15, ty = t >> 4;
    int rl = t >> 3, q4 = (t & 7) * 4;

    int ar1 = r0 + rl, ar2 = ar1 + 32;
    int ar1c = ar1 < NN ? ar1 : NN - 1;
    int ar2c = ar2 < NN ? ar2 : NN - 1;
    const float* Ap1 = A + (size_t)ar1c * D + q4;
    const float* Ap2 = A + (size_t)ar2c * D + q4;
    const float* Wp1 = W + (size_t)(t >> 4) * D + c0 + (t & 15) * 4;
    const float* Wp2 = Wp1 + (size_t)16 * D;

    float4 a0 = *(const float4*)(Ap1);
    float4 a1 = *(const float4*)(Ap2);
    float4 w0 = *(const float4*)(Wp1);
    float4 w1 = *(const float4*)(Wp2);

    float4 acc[4] = {{0,0,0,0},{0,0,0,0},{0,0,0,0},{0,0,0,0}};
    float psa = 0, pda = 0, psb = 0, pdb = 0;

    for (int s = 0; s < 4; ++s) {
        int k0 = s * 32;
        if (s) __syncthreads();                 // prev compute done before LDS overwrite
        At[q4+0][rl]    = a0.x; At[q4+1][rl]    = a0.y; At[q4+2][rl]    = a0.z; At[q4+3][rl]    = a0.w;
        At[q4+0][rl+32] = a1.x; At[q4+1][rl+32] = a1.y; At[q4+2][rl+32] = a1.z; At[q4+3][rl+32] = a1.w;
        ((float4*)&Ws[t >> 4][0])[tx]        = w0;
        ((float4*)&Ws[(t >> 4) + 16][0])[tx] = w1;
        psa += a0.x*wasd[k0+q4] + a0.y*wasd[k0+q4+1] + a0.z*wasd[k0+q4+2] + a0.w*wasd[k0+q4+3];
        pda += a0.x*wasd[128+k0+q4] + a0.y*wasd[128+k0+q4+1] + a0.z*wasd[128+k0+q4+2] + a0.w*wasd[128+k0+q4+3];
        psb += a1.x*wasd[k0+q4] + a1.y*wasd[k0+q4+1] + a1.z*wasd[k0+q4+2] + a1.w*wasd[k0+q4+3];
        pdb += a1.x*wasd[128+k0+q4] + a1.y*wasd[128+k0+q4+1] + a1.z*wasd[128+k0+q4+2] + a1.w*wasd[128+k0+q4+3];
        __syncthreads();
        if (s < 3) {                            // prefetch next tile while computing
            a0 = *(const float4*)(Ap1 + k0 + 32);
            a1 = *(const float4*)(Ap2 + k0 + 32);
            w0 = *(const float4*)(Wp1 + (size_t)(k0 + 32) * D);
            w1 = *(const float4*)(Wp2 + (size_t)(k0 + 32) * D);
        }
        #pragma unroll
        for (int k = 0; k < 32; ++k) {
            float4 wv = ((const float4*)&Ws[k][0])[tx];
            float4 ra = ((const float4*)&At[k][0])[ty];
            float rr[4] = {ra.x, ra.y, ra.z, ra.w};
            #pragma unroll
            for (int i = 0; i < 4; ++i) {
                acc[i].x += rr[i]*wv.x; acc[i].y += rr[i]*wv.y;
                acc[i].z += rr[i]*wv.z; acc[i].w += rr[i]*wv.w;
            }
        }
    }

    #pragma unroll
    for (int i = 0; i < 4; ++i) {
        int r = r0 + ty * 4 + i;
        if (r < NN) {
            if constexpr (sizeof(OutT) == 4) {
                *(float4*)((float*)XP + (size_t)r * D + c0 + tx * 4) = acc[i];
            } else {
                union { uint2 u; __half2 h[2]; } P;
                P.h[0] = __floats2half2_rn(acc[i].x, acc[i].y);
                P.h[1] = __floats2half2_rn(acc[i].z, acc[i].w);
                *(uint2*)((__half*)XP + (size_t)r * D + c0 + tx * 4) = P.u;
            }
        }
    }

    if (ct == 0) {
        redS[rl][t & 7] = psa;      redD[rl][t & 7] = pda;
        redS[rl + 32][t & 7] = psb; redD[rl + 32][t & 7] = pdb;
        __syncthreads();
        if (t < 64) {
            int r = r0 + t;
            if (r < NN) {
                float ss = 0, dd = 0;
                #pragma unroll
                for (int j = 0; j < 8; ++j) { ss += redS[t][j]; dd += redD[t][j]; }
                alpha_s[r] = ss; alpha_d[r] = dd;
            }
        }
    }
}

// ---------------- fp16 aggregation: wave per dst node, quarter-wave per edge row ----------------

__global__ __launch_bounds__(256) void agg_half_k(
        const int* __restrict__ row_ptr, const int* __restrict__ srcs,
        const float* __restrict__ alpha_s, const float* __restrict__ alpha_d,
        const __half* __restrict__ XPH, const float* __restrict__ bias,
        float* __restrict__ OUT) {
    int n = (blockIdx.x * blockDim.x + threadIdx.x) >> 6;
    int lane = threadIdx.x & 63;
    int beg = row_ptr[n], end = row_ptr[n + 1], deg = end - beg;
    float ad = alpha_d[n];

    if (deg <= 64) {
        int sreg = 0;
        float e = -3.4e38f;
        if (lane < deg) {
            sreg = srcs[beg + lane];
            float v = alpha_s[sreg] + ad;
            e = v > 0.f ? v : 0.2f * v;
        }
        float m = e;
        #pragma unroll
        for (int o = 32; o; o >>= 1) m = fmaxf(m, __shfl_xor(m, o));
        float w = (lane < deg) ? __expf(e - m) : 0.f;
        float denom = w;
        #pragma unroll
        for (int o = 32; o; o >>= 1) denom += __shfl_xor(denom, o);

        int qw = lane >> 4, q = lane & 15;
        float acc[8] = {0,0,0,0,0,0,0,0};
        int dgr = (deg + 3) & ~3;
        const uint4* base = (const uint4*)XPH;   // row = 16 uint4
        int j = 0;
        for (; j + 8 <= dgr; j += 8) {
            int e0 = j + qw, e1 = j + 4 + qw;
            int   s0 = __shfl(sreg, e0); float w0 = __shfl(w, e0);
            int   s1 = __shfl(sreg, e1); float w1 = __shfl(w, e1);
            uint4 u0 = base[(size_t)s0 * 16 + q];
            uint4 u1 = base[(size_t)s1 * 16 + q];
            {
                union { uint4 u; __half2 h[4]; } U; U.u = u0;
                float2 f0 = __half22float2(U.h[0]);
                float2 f1 = __half22float2(U.h[1]);
                float2 f2 = __half22float2(U.h[2]);
                float2 f3 = __half22float2(U.h[3]);
                acc[0] += w0*f0.x; acc[1] += w0*f0.y; acc[2] += w0*f1.x; acc[3] += w0*f1.y;
                acc[4] += w0*f2.x; acc[5] += w0*f2.y; acc[6] += w0*f3.x; acc[7] += w0*f3.y;
            }
            {
                union { uint4 u; __half2 h[4]; } U; U.u = u1;
                float2 f0 = __half22float2(U.h[0]);
                float2 f1 = __half22float2(U.h[1]);
                float2 f2 = __half22float2(U.h[2]);
                float2 f3 = __half22float2(U.h[3]);
                acc[0] += w1*f0.x; acc[1] += w1*f0.y; acc[2] += w1*f1.x; acc[3] += w1*f1.y;
                acc[4] += w1*f2.x; acc[5] += w1*f2.y; acc[6] += w1*f3.x; acc[7] += w1*f3.y;
            }
        }
        for (; j < dgr; j += 4) {
            int e0 = j + qw;
            int s0 = __shfl(sreg, e0); float w0 = __shfl(w, e0);
            uint4 u0 = base[(size_t)s0 * 16 + q];
            union { uint4 u; __half2 h[4]; } U; U.u = u0;
            float2 f0 = __half22float2(U.h[0]);
            float2 f1 = __half22float2(U.h[1]);
            float2 f2 = __half22float2(U.h[2]);
            float2 f3 = __half22float2(U.h[3]);
            acc[0] += w0*f0.x; acc[1] += w0*f0.y; acc[2] += w0*f1.x; acc[3] += w0*f1.y;
            acc[4] += w0*f2.x; acc[5] += w0*f2.y; acc[6] += w0*f3.x; acc[7] += w0*f3.y;
        }
        #pragma unroll
        for (int f = 0; f < 8; ++f) {
            acc[f] += __shfl_xor(acc[f], 16);
            acc[f] += __shfl_xor(acc[f], 32);
        }
        if (lane < 16) {
            float inv = 1.f / (denom + 1e-16f);
            const float4* b4 = (const float4*)bias;
            float4 ba = b4[q * 2], bb = b4[q * 2 + 1];
            float4 oA, oB;
            oA.x = gelu_tanh(acc[0]*inv + ba.x); oA.y = gelu_tanh(acc[1]*inv + ba.y);
            oA.z = gelu_tanh(acc[2]*inv + ba.z); oA.w = gelu_tanh(acc[3]*inv + ba.w);
            oB.x = gelu_tanh(acc[4]*inv + bb.x); oB.y = gelu_tanh(acc[5]*inv + bb.y);
            oB.z = gelu_tanh(acc[6]*inv + bb.z); oB.w = gelu_tanh(acc[7]*inv + bb.w);
            float4* o = (float4*)(OUT + (size_t)n * D + q * 8);
            o[0] = oA; o[1] = oB;
        }
    } else {
        // rare fallback (deg > 64): 3-pass, 2 features per lane
        float m = -3.4e38f;
        for (int i = beg + lane; i < end; i += 64) {
            int s = srcs[i];
            float v = alpha_s[s] + ad; v = v > 0.f ? v : 0.2f * v;
            m = fmaxf(m, v);
        }
        #pragma unroll
        for (int o = 32; o; o >>= 1) m = fmaxf(m, __shfl_xor(m, o));
        float denom = 0.f;
        for (int i = beg + lane; i < end; i += 64) {
            int s = srcs[i];
            float v = alpha_s[s] + ad; v = v > 0.f ? v : 0.2f * v;
            denom += __expf(v - m);
        }
        #pragma unroll
        for (int o = 32; o; o >>= 1) denom += __shfl_xor(denom, o);
        float2 acc = {0.f, 0.f};
        for (int i = beg; i < end; ++i) {
            int s = srcs[i];
            float v = alpha_s[s] + ad; v = v > 0.f ? v : 0.2f * v;
            float wgt = __expf(v - m);
            union { unsigned int x; __half2 h; } U;
            U.x = ((const unsigned int*)(XPH + (size_t)s * D))[lane];
            float2 f = __half22float2(U.h);
            acc.x += wgt * f.x; acc.y += wgt * f.y;
        }
        float inv = 1.f / (denom + 1e-16f);
        float2 b2 = ((const float2*)bias)[lane];
        float r0 = gelu_tanh(acc.x * inv + b2.x);
        float r1 = gelu_tanh(acc.y * inv + b2.y);
        ((float2*)(OUT + (size_t)n * D))[lane] = make_float2(r0, r1);
    }
}

// ---------------- fp32 aggregation (layer 3) — unchanged proven R3 code ----------------

__global__ __launch_bounds__(256) void agg_k(
        const int* __restrict__ row_ptr, const int* __restrict__ srcs,
        const float* __restrict__ alpha_s, const float* __restrict__ alpha_d,
        const float* __restrict__ XP, const float* __restrict__ bias,
        float* __restrict__ OUT, int apply_gelu) {
    int n = (blockIdx.x * blockDim.x + threadIdx.x) >> 6;
    int lane = threadIdx.x & 63;
    int beg = row_ptr[n], end = row_ptr[n + 1], deg = end - beg;
    float ad = alpha_d[n];

    if (deg <= 64) {
        int sreg = 0;
        float e = -3.4e38f;
        if (lane < deg) {
            sreg = srcs[beg + lane];
            float v = alpha_s[sreg] + ad;
            e = v > 0.f ? v : 0.2f * v;
        }
        float m = e;
        #pragma unroll
        for (int o = 32; o; o >>= 1) m = fmaxf(m, __shfl_xor(m, o));
        float w = (lane < deg) ? __expf(e - m) : 0.f;
        float denom = w;
        #pragma unroll
        for (int o = 32; o; o >>= 1) denom += __shfl_xor(denom, o);

        int half = lane >> 5, q = lane & 31;
        float4 acc0 = {0,0,0,0}, acc1 = {0,0,0,0};
        int j = 0;
        for (; j + 4 <= deg; j += 4) {
            int   s0 = __shfl(sreg, j + half);
            float w0 = __shfl(w,    j + half);
            int   s1 = __shfl(sreg, j + 2 + half);
            float w1 = __shfl(w,    j + 2 + half);
            float4 x0 = ((const float4*)(XP + (size_t)s0 * D))[q];
            float4 x1 = ((const float4*)(XP + (size_t)s1 * D))[q];
            acc0.x += w0 * x0.x; acc0.y += w0 * x0.y;
            acc0.z += w0 * x0.z; acc0.w += w0 * x0.w;
            acc1.x += w1 * x1.x; acc1.y += w1 * x1.y;
            acc1.z += w1 * x1.z; acc1.w += w1 * x1.w;
        }
        for (; j < deg; j += 2) {
            int ej = j + half;
            int   s0 = __shfl(sreg, ej < 63 ? ej : 63);
            float w0 = __shfl(w,    ej < 63 ? ej : 63);
            if (ej < deg) {
                float4 x0 = ((const float4*)(XP + (size_t)s0 * D))[q];
                acc0.x += w0 * x0.x; acc0.y += w0 * x0.y;
                acc0.z += w0 * x0.z; acc0.w += w0 * x0.w;
            }
        }
        float4 tot;
        tot.x = acc0.x + acc1.x; tot.y = acc0.y + acc1.y;
        tot.z = acc0.z + acc1.z; tot.w = acc0.w + acc1.w;
        tot.x += __shfl_xor(tot.x, 32);
        tot.y += __shfl_xor(tot.y, 32);
        tot.z += __shfl_xor(tot.z, 32);
        tot.w += __shfl_xor(tot.w, 32);

        if (half == 0) {
            float inv = 1.f / (denom + 1e-16f);
            float4 b4 = ((const float4*)bias)[q];
            float r0 = tot.x * inv + b4.x;
            float r1 = tot.y * inv + b4.y;
            float r2 = tot.z * inv + b4.z;
            float r3 = tot.w * inv + b4.w;
            if (apply_gelu) {
                r0 = gelu_tanh(r0); r1 = gelu_tanh(r1);
                r2 = gelu_tanh(r2); r3 = gelu_tanh(r3);
            }
            ((float4*)(OUT + (size_t)n * D))[q] = make_float4(r0, r1, r2, r3);
        }
    } else {
        float m = -3.4e38f;
        for (int i = beg + lane; i < end; i += 64) {
            int s = srcs[i];
            float v = alpha_s[s] + ad;
            v = v > 0.f ? v : 0.2f * v;
            m = fmaxf(m, v);
        }
        #pragma unroll
        for (int o = 32; o; o >>= 1) m = fmaxf(m, __shfl_xor(m, o));
        float denom = 0.f;
        for (int i = beg + lane; i < end; i += 64) {
            int s = srcs[i];
            float v = alpha_s[s] + ad;
            v = v > 0.f ? v : 0.2f * v;
            denom += __expf(v - m);
        }
        #pragma unroll
        for (int o = 32; o; o >>= 1) denom += __shfl_xor(denom, o);
        float2 acc = {0.f, 0.f};
        for (int i = beg; i < end; ++i) {
            int s = srcs[i];
            float v = alpha_s[s] + ad;
            v = v > 0.f ? v : 0.2f * v;
            float wgt = __expf(v - m);
            float2 xv = ((const float2*)(XP + (size_t)s * D))[lane];
            acc.x += wgt * xv.x;
            acc.y += wgt * xv.y;
        }
        float inv = 1.f / (denom + 1e-16f);
        float2 b2 = ((const float2*)bias)[lane];
        float r0 = acc.x * inv + b2.x;
        float r1 = acc.y * inv + b2.y;
        if (apply_gelu) { r0 = gelu_tanh(r0); r1 = gelu_tanh(r1); }
        ((float2*)(OUT + (size_t)n * D))[lane] = make_float2(r0, r1);
    }
}

// ---------------- launch ----------------

extern "C" void kernel_launch(void* const* d_in, const int* in_sizes, int n_in,
                              void* d_out, int out_size, void* d_ws, size_t ws_size,
                              hipStream_t stream) {
    const float* x    = (const float*)d_in[0];
    const int*   ei   = (const int*)d_in[1];
    const float* W    = (const float*)d_in[2];
    const float* asrc = (const float*)d_in[3];
    const float* adst = (const float*)d_in[4];
    const float* bias = (const float*)d_in[5];
    float* out = (float*)d_out;

    const int* src_arr = ei;
    const int* dst_arr = ei + NE;

    char* ws = (char*)d_ws;
    size_t off = 0;
    auto alloc = [&](size_t bytes) { char* p = ws + off; off += (bytes + 255) & ~(size_t)255; return p; };
    float*  xp      = (float*)alloc((size_t)NN * D * sizeof(float));
    __half* xph     = (__half*)alloc((size_t)NN * D * sizeof(__half));
    float*  hbuf    = (float*)alloc((size_t)NN * D * sizeof(float));
    float*  alpha_s = (float*)alloc(NN * sizeof(float));
    float*  alpha_d = (float*)alloc(NN * sizeof(float));
    float*  wasd    = (float*)alloc(3 * 256 * sizeof(float));
    int* counts    = (int*)alloc(NN * sizeof(int));
    int* row_ptr   = (int*)alloc((NN + 1) * sizeof(int));
    int* write_ptr = (int*)alloc(NN * sizeof(int));
    int* blk_sums  = (int*)alloc(NB * sizeof(int));
    int* blk_offs  = (int*)alloc(NB * sizeof(int));
    int* srcs      = (int*)alloc((size_t)ETOT * sizeof(int));
    (void)ws_size; (void)in_sizes; (void)n_in; (void)out_size;

    hipMemsetAsync(counts, 0, NN * sizeof(int), stream);
    int eb = (ETOT + 255) / 256;
    count_k<<<eb, 256, 0, stream>>>(dst_arr, counts);
    scan1_k<<<NB, 256, 0, stream>>>(counts, blk_sums);
    scan2_k<<<1, 64, 0, stream>>>(blk_sums, blk_offs, row_ptr);
    scan3_k<<<NB, 256, 0, stream>>>(counts, blk_offs, row_ptr, write_ptr);
    scatter_k<<<eb, 256, 0, stream>>>(src_arr, dst_arr, write_ptr, srcs);

    wasd_k<<<3, 256, 0, stream>>>(W, asrc, adst, wasd);

    int gemm_blocks = 2 * ((NN + 63) / 64);   // 1564
    int agg_blocks  = NN / 4;                 // 12500

    // layer 0: fp16 xp
    gemm_k<__half><<<gemm_blocks, 256, 0, stream>>>(x, W, wasd, xph, alpha_s, alpha_d);
    agg_half_k<<<agg_blocks, 256, 0, stream>>>(row_ptr, srcs, alpha_s, alpha_d, xph,
                                               bias, hbuf);
    // layer 1: fp16 xp
    gemm_k<__half><<<gemm_blocks, 256, 0, stream>>>(hbuf, W + (size_t)1 * D * D,
                                                    wasd + 256, xph, alpha_s, alpha_d);
    agg_half_k<<<agg_blocks, 256, 0, stream>>>(row_ptr, srcs, alpha_s, alpha_d, xph,
                                               bias + D, out);
    // layer 2: fp32 xp (output precision)
    gemm_k<float><<<gemm_blocks, 256, 0, stream>>>(out, W + (size_t)2 * D * D,
                                                   wasd + 512, xp, alpha_s, alpha_d);
    agg_k<<<agg_blocks, 256, 0, stream>>>(row_ptr, srcs, alpha_s, alpha_d, xp,
                                          bias + 2 * D, out, 0);
}